// Round 8
// baseline (342.278 us; speedup 1.0000x reference)
//
#include <hip/hip_runtime.h>
#include <hip/hip_bf16.h>
#include <cstdint>

#define HH 128
#define XX 128

typedef __attribute__((ext_vector_type(8))) short short8;
typedef __attribute__((ext_vector_type(4))) short short4_;
typedef __attribute__((ext_vector_type(4))) float float4_;
typedef __attribute__((ext_vector_type(8))) _Float16 half8_;
typedef __attribute__((ext_vector_type(2))) _Float16 half2_;
typedef __attribute__((ext_vector_type(2))) unsigned int uint2_;
typedef __attribute__((ext_vector_type(4))) unsigned int uint4_;

__device__ __forceinline__ float sigmoidf_(float x) {
  return 1.f / (1.f + __expf(-x));
}
__device__ __forceinline__ float tanhf_(float x) {
  float e = __expf(-2.f * fabsf(x));
  float t = (1.f - e) / (1.f + e);
  return copysignf(t, x);
}

// ================= CSR build =================
__global__ __launch_bounds__(256) void hist_kernel(const int* __restrict__ dst,
                                                   int* __restrict__ cnt, int E) {
  int e = blockIdx.x * 256 + threadIdx.x;
  if (e < E) atomicAdd(&cnt[dst[e]], 1);
}

__global__ __launch_bounds__(256) void scan_block_sum(const int* __restrict__ cnt,
                                                      int* __restrict__ bsum) {
  __shared__ int red[256];
  int b = blockIdx.x, t = threadIdx.x;
  int base = b * 1024 + t * 4;
  int s = cnt[base] + cnt[base + 1] + cnt[base + 2] + cnt[base + 3];
  red[t] = s;
  __syncthreads();
  for (int off = 128; off > 0; off >>= 1) {
    if (t < off) red[t] += red[t + off];
    __syncthreads();
  }
  if (t == 0) bsum[b] = red[0];
}

__global__ __launch_bounds__(256) void scan_top(const int* __restrict__ bsum,
                                                int* __restrict__ boff,
                                                int* __restrict__ row_ptr, int N,
                                                int E) {
  __shared__ int tmp[256];
  int t = threadIdx.x;
  int own = bsum[t];
  tmp[t] = own;
  __syncthreads();
  for (int off = 1; off < 256; off <<= 1) {
    int x = (t >= off) ? tmp[t - off] : 0;
    __syncthreads();
    tmp[t] += x;
    __syncthreads();
  }
  boff[t] = tmp[t] - own;  // exclusive
  if (t == 0) row_ptr[N] = E;
}

__global__ __launch_bounds__(256) void scan_fill(const int* __restrict__ cnt,
                                                 const int* __restrict__ boff,
                                                 int* __restrict__ row_ptr,
                                                 int* __restrict__ row_fill) {
  __shared__ int tsum[256];
  int b = blockIdx.x, t = threadIdx.x;
  int base = b * 1024 + t * 4;
  int v0 = cnt[base], v1 = cnt[base + 1], v2 = cnt[base + 2], v3 = cnt[base + 3];
  int s = v0 + v1 + v2 + v3;
  tsum[t] = s;
  __syncthreads();
  for (int off = 1; off < 256; off <<= 1) {
    int x = (t >= off) ? tsum[t - off] : 0;
    __syncthreads();
    tsum[t] += x;
    __syncthreads();
  }
  int excl = tsum[t] - s + boff[b];
  int p0 = excl, p1 = p0 + v0, p2 = p1 + v1, p3 = p2 + v2;
  row_ptr[base] = p0;
  row_ptr[base + 1] = p1;
  row_ptr[base + 2] = p2;
  row_ptr[base + 3] = p3;
  row_fill[base] = p0;
  row_fill[base + 1] = p1;
  row_fill[base + 2] = p2;
  row_fill[base + 3] = p3;
}

__global__ __launch_bounds__(256) void fill_kernel(const int* __restrict__ src,
                                                   const int* __restrict__ dst,
                                                   int* __restrict__ row_fill,
                                                   int* __restrict__ edge_src,
                                                   int E) {
  int e = blockIdx.x * 256 + threadIdx.x;
  if (e >= E) return;
  int pos = atomicAdd(&row_fill[dst[e]], 1);
  edge_src[pos] = src[e];
}

// ================= weight prep (f16, B-fragment order) =================
__global__ __launch_bounds__(256) void prep_kernel(
    const float* __restrict__ W_iou, const float* __restrict__ U_iou,
    const float* __restrict__ b_iou, const float* __restrict__ U_f_w,
    const float* __restrict__ U_f_b, const float* __restrict__ W_f_w,
    const float* __restrict__ b_f, unsigned short* __restrict__ Bh,
    float* __restrict__ bias) {
  int tid = blockIdx.x * 256 + threadIdx.x;  // 0..16383
  int kg = tid & 3;
  int c16 = (tid >> 2) & 15;
  int ks = (tid >> 6) & 7;
  int w = (tid >> 9) & 7;
  int g = (tid >> 12) & 3;
  int col = w * 16 + c16;
  int kbase = ks * 32 + kg * 8;
#pragma unroll
  for (int j = 0; j < 8; ++j) {
    int k = kbase + j;
    float v;
    if (g < 3) {
      v = (k < 128) ? W_iou[(size_t)(g * 128 + col) * 128 + k]
                    : U_iou[(size_t)(g * 128 + col) * 128 + (k - 128)];
    } else {
      v = (k < 128) ? W_f_w[(size_t)col * 128 + k]
                    : U_f_w[(size_t)col * 128 + (k - 128)];
    }
    Bh[(size_t)tid * 8 + j] = __builtin_bit_cast(unsigned short, (_Float16)v);
  }
  if (tid < 512) {
    int gg = tid >> 7, cc = tid & 127;
    bias[tid] = (gg < 3) ? b_iou[gg * 128 + cc] : (U_f_b[cc] + b_f[cc]);
  }
}

// ================= barrier-free CSR gather =================
// One wave per 4 nodes, 16 lanes per node, no LDS, no barriers.
// Writes per node (into sums == out_h buffer, 512 B per row):
//   bytes [0,256):   h_sum as f16, halfs at off = k ^ ((node&7)<<3)
//   bytes [256,512): c_sum as f16, same swizzle
__global__ __launch_bounds__(256, 8) void gather_kernel(
    const float* __restrict__ h, const float* __restrict__ c,
    const int* __restrict__ row_ptr, const int* __restrict__ edge_src,
    float* __restrict__ sums) {
  const int gt = blockIdx.x * 256 + threadIdx.x;
  const int wid = gt >> 6;
  const int lane = gt & 63;
  const int node = (wid << 2) + (lane >> 4);
  const int sub = lane & 15;

  const int e0 = row_ptr[node];
  const int e1 = row_ptr[node + 1];

  float hs[8] = {0.f, 0.f, 0.f, 0.f, 0.f, 0.f, 0.f, 0.f};
  float cs[8] = {0.f, 0.f, 0.f, 0.f, 0.f, 0.f, 0.f, 0.f};

  for (int e = e0; e < e1; ++e) {
    int s = edge_src[e];
    const float* hp = h + (size_t)s * HH + sub * 8;
    const float* cp = c + (size_t)s * HH + sub * 8;
    float4_ h0 = *reinterpret_cast<const float4_*>(hp);
    float4_ h1 = *reinterpret_cast<const float4_*>(hp + 4);
    float4_ c0 = *reinterpret_cast<const float4_*>(cp);
    float4_ c1 = *reinterpret_cast<const float4_*>(cp + 4);
#pragma unroll
    for (int j = 0; j < 4; ++j) {
      hs[j] += h0[j];
      hs[4 + j] += h1[j];
      cs[j] += c0[j];
      cs[4 + j] += c1[j];
    }
  }

  uint4_ hv, cv;
#pragma unroll
  for (int i = 0; i < 4; ++i) {
    hv[i] = __builtin_bit_cast(unsigned int,
                               __builtin_amdgcn_cvt_pkrtz(hs[2 * i], hs[2 * i + 1]));
    cv[i] = __builtin_bit_cast(unsigned int,
                               __builtin_amdgcn_cvt_pkrtz(cs[2 * i], cs[2 * i + 1]));
  }
  int off = (sub * 8) ^ ((node & 7) << 3);  // in halfs, 16B-aligned
  char* row = (char*)sums + (size_t)node * 512;
  *reinterpret_cast<uint4_*>(row + off * 2) = hv;
  *reinterpret_cast<uint4_*>(row + 256 + off * 2) = cv;
}

// ================= fused MFMA GEMM + gates (regular, no gather) =============
// 64-node tile, 512 threads (8 waves), LDS 64 KB -> 2 blocks/CU.
// LDS halfs: te [0,8192) ; h [8192,16384) ; sums image [16384,32768)
//   (sums image = 64 rows x 512 B: hsum halfs [0,128)+swz, csum [128,256)+swz)
// After compute, reused as f32 words: oh [0,8192), oc [8192,16384).
__device__ __forceinline__ void stage_pk(unsigned short* su, int baseH, int node,
                                         int k4, float4_ v) {
  unsigned int u0 = __builtin_bit_cast(unsigned int,
                                       __builtin_amdgcn_cvt_pkrtz(v[0], v[1]));
  unsigned int u1 = __builtin_bit_cast(unsigned int,
                                       __builtin_amdgcn_cvt_pkrtz(v[2], v[3]));
  int off = k4 ^ ((node & 7) << 3);
  *reinterpret_cast<uint2_*>(&su[baseH + node * 128 + off]) = (uint2_){u0, u1};
}

__device__ __forceinline__ half8_ read_frag128(const unsigned short* su, int baseH,
                                               int node, int kbase, int lane) {
  int k = kbase + ((lane >> 4) << 3);
  int off = k ^ ((node & 7) << 3);
  short8 s = *reinterpret_cast<const short8*>(&su[baseH + node * 128 + off]);
  return __builtin_bit_cast(half8_, s);
}

__device__ __forceinline__ half8_ read_fragS(const unsigned short* su, int node,
                                             int kbase, int lane) {
  int k = kbase + ((lane >> 4) << 3);
  int off = k ^ ((node & 7) << 3);
  short8 s = *reinterpret_cast<const short8*>(&su[16384 + node * 256 + off]);
  return __builtin_bit_cast(half8_, s);
}

__device__ __forceinline__ int cw(int row, int col) {  // output-assembly word
  return row * 128 + (col ^ ((row & 7) << 2));
}

__global__ __launch_bounds__(512, 4) void fused_mfma_kernel(
    const float* __restrict__ te, const float* __restrict__ h,
    const float* __restrict__ sums, const unsigned short* __restrict__ Bh,
    const float* __restrict__ bias, float* __restrict__ out_h,
    float* __restrict__ out_c) {
  __shared__ float4_ smem4[4096];  // 65536 bytes
  unsigned short* su = (unsigned short*)smem4;

  const int t = threadIdx.x;
  const int node0 = blockIdx.x * 64;

  // Stage sums image: pure 16-B copies (swizzle already in the data).
  {
    const char* sbase = (const char*)sums + (size_t)node0 * 512;
    char* dbase = (char*)smem4 + 32768;
#pragma unroll
    for (int i = 0; i < 4; ++i) {
      int q = t + i * 512;  // 0..2047 16-B chunks
      *reinterpret_cast<uint4_*>(dbase + q * 16) =
          *reinterpret_cast<const uint4_*>(sbase + q * 16);
    }
  }
  // Stage te and own-h as f16 (pkrtz).
#pragma unroll
  for (int i = 0; i < 4; ++i) {
    int q = t + i * 512;  // 0..2047 float4-chunks
    int node = q >> 5;
    int k4 = (q & 31) * 4;
    float4_ v =
        *reinterpret_cast<const float4_*>(te + (size_t)(node0 + node) * XX + k4);
    stage_pk(su, 0, node, k4, v);
    v = *reinterpret_cast<const float4_*>(h + (size_t)(node0 + node) * HH + k4);
    stage_pk(su, 8192, node, k4, v);
  }
  __syncthreads();

  const int lane = t & 63;
  const int wave = t >> 6;
  const int wc = wave * 16;  // column base (one 16-col group, all 4 gates)
  const int cl = lane & 15;
  const int kq = lane >> 4;

  float4_ acc[4][4];  // [gate][m], bias added at epilogue
#pragma unroll
  for (int g = 0; g < 4; ++g)
#pragma unroll
    for (int m = 0; m < 4; ++m) acc[g][m] = (float4_){0.f, 0.f, 0.f, 0.f};

  for (int ks = 0; ks < 8; ++ks) {
    half8_ bh[4];
#pragma unroll
    for (int g = 0; g < 4; ++g) {
      size_t boff = (size_t)(((g * 8 + wave) * 8 + ks) * 512) + cl * 32 + kq * 8;
      bh[g] = __builtin_bit_cast(half8_,
                                 *reinterpret_cast<const short8*>(&Bh[boff]));
    }
    if (ks < 4) {
      int kbase = ks * 32;
#pragma unroll
      for (int m = 0; m < 4; ++m) {
        half8_ ah = read_frag128(su, 0, m * 16 + cl, kbase, lane);
#pragma unroll
        for (int g = 0; g < 4; ++g)
          acc[g][m] = __builtin_amdgcn_mfma_f32_16x16x32_f16(ah, bh[g],
                                                             acc[g][m], 0, 0, 0);
      }
    } else {
      int kbase = (ks - 4) * 32;
#pragma unroll
      for (int m = 0; m < 4; ++m) {
        half8_ ah = read_fragS(su, m * 16 + cl, kbase, lane);
        half8_ fh = read_frag128(su, 8192, m * 16 + cl, kbase, lane);
#pragma unroll
        for (int g = 0; g < 3; ++g)
          acc[g][m] = __builtin_amdgcn_mfma_f32_16x16x32_f16(ah, bh[g],
                                                             acc[g][m], 0, 0, 0);
        acc[3][m] = __builtin_amdgcn_mfma_f32_16x16x32_f16(fh, bh[3],
                                                           acc[3][m], 0, 0, 0);
      }
    }
  }

  // Epilogue part 1: pull c_sum (f16) + bias into regs before LDS reuse.
  const int col = wc + cl;
  float bi = bias[0 * 128 + col];
  float bo = bias[1 * 128 + col];
  float bu = bias[2 * 128 + col];
  float bf = bias[3 * 128 + col];
  float csv[4][4];
#pragma unroll
  for (int m = 0; m < 4; ++m)
#pragma unroll
    for (int r = 0; r < 4; ++r) {
      int row = m * 16 + kq * 4 + r;
      unsigned short hb =
          su[16384 + row * 256 + 128 + (col ^ ((row & 7) << 3))];
      csv[m][r] = (float)__builtin_bit_cast(_Float16, hb);
    }

  __syncthreads();  // all LDS reads done; safe to reuse for output assembly

  float* oh = (float*)smem4;         // words [0,8192): h_new rows
  float* oc = (float*)smem4 + 8192;  // words [8192,16384): c_new rows

  // Epilogue part 2: gates -> swizzled LDS assembly.
#pragma unroll
  for (int m = 0; m < 4; ++m)
#pragma unroll
    for (int r = 0; r < 4; ++r) {
      int rowl = m * 16 + kq * 4 + r;
      float ig = sigmoidf_(acc[0][m][r] + bi);
      float og = sigmoidf_(acc[1][m][r] + bo);
      float ug = tanhf_(acc[2][m][r] + bu);
      float fg = sigmoidf_(acc[3][m][r] + bf);
      float cn = fmaf(ig, ug, fg * csv[m][r]);
      int wadr = cw(rowl, col);
      oc[wadr] = cn;
      oh[wadr] = og * tanhf_(cn);
    }
  __syncthreads();

  // Stream outputs: fully coalesced float4 rows.
#pragma unroll
  for (int i = 0; i < 4; ++i) {
    int q = t + i * 512;
    int rr = q >> 5;
    int k4 = (q & 31) * 4;
    int wadr = rr * 128 + (k4 ^ ((rr & 7) << 2));
    *reinterpret_cast<float4_*>(out_h + (size_t)(node0 + rr) * HH + k4) =
        *reinterpret_cast<const float4_*>(&oh[wadr]);
    *reinterpret_cast<float4_*>(out_c + (size_t)(node0 + rr) * HH + k4) =
        *reinterpret_cast<const float4_*>(&oc[wadr]);
  }
}

extern "C" void kernel_launch(void* const* d_in, const int* in_sizes, int n_in,
                              void* d_out, int out_size, void* d_ws, size_t ws_size,
                              hipStream_t stream) {
  const float* te = (const float*)d_in[0];
  const float* h = (const float*)d_in[1];
  const float* c = (const float*)d_in[2];
  const int* src = (const int*)d_in[3];
  const int* dst = (const int*)d_in[4];
  const float* W_iou = (const float*)d_in[5];
  const float* U_iou = (const float*)d_in[6];
  const float* b_iou = (const float*)d_in[7];
  const float* U_f_w = (const float*)d_in[8];
  const float* U_f_b = (const float*)d_in[9];
  const float* W_f_w = (const float*)d_in[10];
  const float* b_f = (const float*)d_in[11];

  const int N = in_sizes[1] / HH;
  const int E = in_sizes[3];

  float* out_h = (float*)d_out;           // gather writes f16 sums here first
  float* out_c = out_h + (size_t)N * HH;

  // workspace carve-up
  char* ws = (char*)d_ws;
  unsigned short* Bh = (unsigned short*)ws;              // 256 KB
  float* bias = (float*)(Bh + 4 * 8 * 8 * 16 * 4 * 8);   // 2 KB
  int* cnt = (int*)(bias + 512);                         // N ints
  int* row_ptr = cnt + N;                                // N+4 ints
  int* row_fill = row_ptr + N + 4;                       // N ints
  int* edge_src = row_fill + N;                          // E ints
  int* bsum = edge_src + E;                              // 256
  int* boff = bsum + 256;                                // 256

  hipMemsetAsync(cnt, 0, (size_t)N * sizeof(int), stream);

  hist_kernel<<<(E + 255) / 256, 256, 0, stream>>>(dst, cnt, E);
  scan_block_sum<<<N / 1024, 256, 0, stream>>>(cnt, bsum);
  scan_top<<<1, 256, 0, stream>>>(bsum, boff, row_ptr, N, E);
  scan_fill<<<N / 1024, 256, 0, stream>>>(cnt, boff, row_ptr, row_fill);
  fill_kernel<<<(E + 255) / 256, 256, 0, stream>>>(src, dst, row_fill, edge_src, E);

  prep_kernel<<<64, 256, 0, stream>>>(W_iou, U_iou, b_iou, U_f_w, U_f_b, W_f_w,
                                      b_f, Bh, bias);

  gather_kernel<<<N / 16, 256, 0, stream>>>(h, c, row_ptr, edge_src, out_h);

  fused_mfma_kernel<<<N / 64, 512, 0, stream>>>(te, h, out_h, Bh, bias, out_h,
                                                out_c);
}